// Round 3
// baseline (220.199 us; speedup 1.0000x reference)
//
#include <hip/hip_runtime.h>
#include <hip/hip_bf16.h>

#define NR 16384
#define CC 2048
#define NV 6
#define MOMENT_F 1.6384f          // N/10000
#define SEGS 256
#define LSEG (NR / SEGS)          // 64 rows per segment
#define PF 8                      // loads in flight per wave
#define NCHUNK 8
#define SEG_PER_CHUNK (SEGS / NCHUNK)  // 32

// part : SEGS*NV slabs of 4096 floats: [512 float4 sums][512 float4 sqsums]
// part2: NCHUNK*NV slabs, same per-slab layout. Both fully overwritten each
// call -> no zero-init needed anywhere.

// ---------------------------------------------------------------------------
// K1: grid = SEGS*NV blocks x 512 thr. Block (s,v): compact matching rows of
// its 64-row segment into LDS, then stream rows (1 float4/thread/row) in
// batches of PF independent loads; write per-block slab with plain stores.
// __launch_bounds__(512,4): VGPR cap 128 so the compiler can keep PF=8
// dwordx4 loads in flight (R1/R2 allocated only 32 VGPRs -> latency-bound).
// ---------------------------------------------------------------------------
__global__ __launch_bounds__(512, 4) void k1_segstats(
    const float* __restrict__ x, const int* __restrict__ views,
    float4* __restrict__ part4) {
  const int s = blockIdx.x / NV;
  const int v = blockIdx.x - s * NV;
  const int r0 = s * LSEG;
  const int t = threadIdx.x;

  __shared__ int list[LSEG];
  __shared__ int cnt;
  if (t == 0) cnt = 0;
  __syncthreads();
  if (t < LSEG) {
    if (views[r0 + t] == v) list[atomicAdd(&cnt, 1)] = r0 + t;
  }
  __syncthreads();
  const int m = cnt;

  const float4* xp = (const float4*)x + t;  // thread's column group
  float4 s4 = {0.f, 0.f, 0.f, 0.f};
  float4 q4 = {0.f, 0.f, 0.f, 0.f};

  for (int j = 0; j < m; j += PF) {
    float4 a[PF];
#pragma unroll
    for (int i = 0; i < PF; ++i)
      if (j + i < m) a[i] = xp[list[j + i] * 512];  // uniform predicate
#pragma unroll
    for (int i = 0; i < PF; ++i)
      if (j + i < m) {
        s4.x += a[i].x; s4.y += a[i].y; s4.z += a[i].z; s4.w += a[i].w;
        q4.x = fmaf(a[i].x, a[i].x, q4.x);
        q4.y = fmaf(a[i].y, a[i].y, q4.y);
        q4.z = fmaf(a[i].z, a[i].z, q4.z);
        q4.w = fmaf(a[i].w, a[i].w, q4.w);
      }
  }

  float4* slab = part4 + (size_t)blockIdx.x * 1024;  // blockIdx.x == s*NV+v
  slab[t]       = s4;
  slab[512 + t] = q4;
}

// ---------------------------------------------------------------------------
// K1b: reduce 256 segment slabs -> 8 chunk slabs. Grid 192 x 256. Thread
// (chunk,v,c4) sums 32 float4 partials, plain store (no atomics, no init).
// ---------------------------------------------------------------------------
__global__ __launch_bounds__(256) void k1b_reduce(
    const float4* __restrict__ part4, float4* __restrict__ part24) {
  const int u = blockIdx.x * 256 + threadIdx.x;  // 0 .. 8*6*1024-1
  const int c4 = u & 1023;
  const int vv = u >> 10;        // ci*NV + v, 0..47
  const int ci = vv / NV;
  const int v  = vv - ci * NV;
  const int s0 = ci * SEG_PER_CHUNK;
  float4 acc = {0.f, 0.f, 0.f, 0.f};
#pragma unroll 8
  for (int i = 0; i < SEG_PER_CHUNK; ++i) {
    float4 p = part4[(size_t)((s0 + i) * NV + v) * 1024 + c4];
    acc.x += p.x; acc.y += p.y; acc.z += p.z; acc.w += p.w;
  }
  part24[(size_t)vv * 1024 + c4] = acc;
}

// ---------------------------------------------------------------------------
// K2: single block x 1024 thr. Recompute per-view counts from views (64 KB),
// finish chunk reduction + stats + loss per column (2 cols/thread), block
// reduce, plain-store out (full overwrite -> no d_out memset needed).
// ---------------------------------------------------------------------------
__global__ __launch_bounds__(1024) void k2_finish(
    const float* __restrict__ part2, const int* __restrict__ views,
    const float* __restrict__ cmean, const float* __restrict__ cstd,
    float* __restrict__ out) {
  const int t = threadIdx.x;
  const int lane = t & 63;
  const int w = t >> 6;

  // --- counts from views ---
  float c6[NV] = {0.f, 0.f, 0.f, 0.f, 0.f, 0.f};
  const int4* v4 = (const int4*)views;
#pragma unroll
  for (int it = 0; it < NR / 4 / 1024; ++it) {
    int4 q = v4[t + it * 1024];
#pragma unroll
    for (int v = 0; v < NV; ++v)
      c6[v] += (float)((q.x == v) + (q.y == v) + (q.z == v) + (q.w == v));
  }
#pragma unroll
  for (int v = 0; v < NV; ++v)
    for (int o = 32; o > 0; o >>= 1) c6[v] += __shfl_down(c6[v], o, 64);
  __shared__ float lcnt[16][NV];
  __shared__ float cnt_s[NV];
  if (lane == 0)
#pragma unroll
    for (int v = 0; v < NV; ++v) lcnt[w][v] = c6[v];
  __syncthreads();
  if (t < NV) {
    float s = 0.f;
#pragma unroll
    for (int i = 0; i < 16; ++i) s += lcnt[i][t];
    cnt_s[t] = s;
  }
  __syncthreads();

  float cnt[NV];
  float nvalid = 0.f;
#pragma unroll
  for (int v = 0; v < NV; ++v) {
    cnt[v] = cnt_s[v];
    nvalid += (cnt[v] > 1.5f) ? 1.f : 0.f;
  }

  // --- per-column stats + loss, 2 cols per thread ---
  float contrib = 0.f;
#pragma unroll
  for (int half = 0; half < 2; ++half) {
    const int c = t + half * 1024;
    float mean[NV], sd[NV];
    float nm = 0.f, ns = 0.f;
#pragma unroll
    for (int v = 0; v < NV; ++v) {
      float su = 0.f, sq = 0.f;
#pragma unroll
      for (int ch = 0; ch < NCHUNK; ++ch) {
        const float* sl = part2 + (size_t)(ch * NV + v) * 4096;
        su += sl[c];
        sq += sl[2048 + c];
      }
      float n = fmaxf(cnt[v], 1.f);
      float mu = su / n;
      float var = (sq - cnt[v] * mu * mu) / fmaxf(cnt[v] - 1.f, 1.f);
      float sdv = sqrtf(fmaxf(var, 0.f));
      mean[v] = mu;
      sd[v] = sdv;
      if (cnt[v] > 1.5f) { nm += mu; ns += sdv; }
    }
    nm /= nvalid;
    ns /= nvalid;
    const float cm = cmean[c] * (1.f - MOMENT_F) + nm * MOMENT_F;
    const float cs = cstd[c]  * (1.f - MOMENT_F) + ns * MOMENT_F;
#pragma unroll
    for (int v = 0; v < NV; ++v)
      if (cnt[v] > 1.5f) {
        float d1 = mean[v] - cm;
        float d2 = sd[v] - cs;
        contrib += d1 * d1 + d2 * d2;
      }
  }
  contrib /= (2.f * nvalid);

  for (int o = 32; o > 0; o >>= 1) contrib += __shfl_down(contrib, o, 64);
  __shared__ float wsum[16];
  if (lane == 0) wsum[w] = contrib;
  __syncthreads();
  if (t == 0) {
    float tot = 0.f;
#pragma unroll
    for (int i = 0; i < 16; ++i) tot += wsum[i];
    out[0] = tot;
  }
}

extern "C" void kernel_launch(void* const* d_in, const int* in_sizes, int n_in,
                              void* d_out, int out_size, void* d_ws, size_t ws_size,
                              hipStream_t stream) {
  const float* x     = (const float*)d_in[0];  // (N, C) f32
  const float* cmean = (const float*)d_in[1];  // (C,)  f32
  const float* cstd  = (const float*)d_in[2];  // (C,)  f32
  const int*   views = (const int*)d_in[3];    // (N,)  i32
  float* out = (float*)d_out;

  // ws layout: [part: SEGS*NV*4096 f][part2: NCHUNK*NV*4096 f]  (~26 MB of
  // the 512 MB workspace; everything fully overwritten -> no memsets).
  float* part  = (float*)d_ws;
  float* part2 = part + (size_t)SEGS * NV * 4096;

  k1_segstats<<<SEGS * NV, 512, 0, stream>>>(x, views, (float4*)part);
  k1b_reduce<<<NCHUNK * NV * 1024 / 256, 256, 0, stream>>>(
      (const float4*)part, (float4*)part2);
  k2_finish<<<1, 1024, 0, stream>>>(part2, views, cmean, cstd, out);
}